// Round 6
// baseline (309.728 us; speedup 1.0000x reference)
//
#include <hip/hip_runtime.h>
#include <math.h>

// CausalSelfAttention: B=2, T=2048, C=1024, H=16, Dh=64. fp32 in/out.
//  1. cvt x -> bf16; cvt Wqkv/Wproj -> bf16 TRANSPOSED ([N][K])
//  2. bf16 MFMA GEMM qkv -> Q bf16 (prescaled 0.125*log2e) [bh][t][64],
//     K bf16 [bh][t][64], V bf16 TRANSPOSED [bh][64][t] (packed 8B stores)
//  3. MFMA flash attention: 4 indep waves/block, NO barriers (per-wave P
//     buffer + in-order LDS), static-max exp2 softmax, K-prefetch pipeline
//  4. bf16 MFMA GEMM out = y @ Wproj + bproj (fp32 out)

typedef __attribute__((ext_vector_type(8))) short short8;
typedef __attribute__((ext_vector_type(4))) short short4v;
typedef __attribute__((ext_vector_type(4))) float floatx4;

__device__ __forceinline__ unsigned short f2bf(float f) {
  unsigned u = __float_as_uint(f);
  return (unsigned short)((u + 0x7fff + ((u >> 16) & 1)) >> 16);
}

__device__ __forceinline__ void async16(const void* g, void* l) {
  __builtin_amdgcn_global_load_lds(
      (const __attribute__((address_space(1))) unsigned int*)g,
      (__attribute__((address_space(3))) unsigned int*)l, 16, 0, 0);
}

// ---------------- conversion kernels ----------------

__global__ __launch_bounds__(256) void cvt_bf16(const float* __restrict__ in,
                                                unsigned short* __restrict__ out,
                                                int n4) {
  int i = blockIdx.x * 256 + threadIdx.x;
  if (i < n4) {
    float4 v = ((const float4*)in)[i];
    uint2 p;
    p.x = (unsigned)f2bf(v.x) | ((unsigned)f2bf(v.y) << 16);
    p.y = (unsigned)f2bf(v.z) | ((unsigned)f2bf(v.w) << 16);
    ((uint2*)out)[i] = p;
  }
}

// in: [K][N] fp32 row-major; out: [N][K] bf16 row-major (transpose)
__global__ __launch_bounds__(256) void cvt_transpose(
    const float* __restrict__ in, unsigned short* __restrict__ out, int K, int N) {
  __shared__ __align__(16) unsigned short t[64][72];
  int k0 = blockIdx.y * 64, n0 = blockIdx.x * 64;
  int tid = threadIdx.x;
#pragma unroll
  for (int r = 0; r < 4; ++r) {
    int k = (tid >> 4) + r * 16;
    int n = (tid & 15) * 4;
    float4 v = *(const float4*)(in + (size_t)(k0 + k) * N + n0 + n);
    t[n + 0][k] = f2bf(v.x);
    t[n + 1][k] = f2bf(v.y);
    t[n + 2][k] = f2bf(v.z);
    t[n + 3][k] = f2bf(v.w);
  }
  __syncthreads();
#pragma unroll
  for (int r = 0; r < 2; ++r) {
    int n = (tid >> 3) + r * 32;
    int c = tid & 7;
    int4 v = *(const int4*)(&t[n][c * 8]);
    *(int4*)(out + (size_t)(n0 + n) * K + k0 + c * 8) = v;
  }
}

// ---------------- bf16 MFMA GEMM ----------------
// C[M,N] = A[M,K] @ B[K,N] + bias;  A: bf16 [M][K], Bt: bf16 [N][K] (B^T).
// 128x128 tile, BK=64, 4 waves (2x2 of 64x64), 16x16x32 bf16 MFMA.
// MODE 0: scatter epilogue -> bf16 Q (prescaled), K, V^T. MODE 1: fp32 row-major.
template <int MODE>
__global__ __launch_bounds__(256, 2) void gemm_bf16(
    const unsigned short* __restrict__ A, const unsigned short* __restrict__ Bt,
    const float* __restrict__ bias, float* __restrict__ Cout,
    unsigned short* __restrict__ Qb, unsigned short* __restrict__ Kb,
    unsigned short* __restrict__ Vt, int M, int N, int K) {
  __shared__ __align__(16) unsigned short As[8 * 1024];
  __shared__ __align__(16) unsigned short Bs[8 * 1024];

  const int tid = threadIdx.x;
  const int lane = tid & 63;
  const int wave = tid >> 6;
  const int wm = wave >> 1, wn = wave & 1;
  const int quad = lane >> 4;
  const int l15 = lane & 15;
  const int row0 = blockIdx.y * 128, col0 = blockIdx.x * 128;

  floatx4 acc[4][4];
#pragma unroll
  for (int i = 0; i < 4; ++i)
#pragma unroll
    for (int j = 0; j < 4; ++j) acc[i][j] = (floatx4)0.0f;

  for (int k0 = 0; k0 < K; k0 += 64) {
    __syncthreads();
#pragma unroll
    for (int ti = 0; ti < 4; ++ti) {
      int t = wave * 4 + ti;
      int kc = t >> 1;
      int m0 = (t & 1) << 6;
      async16(A + (size_t)(row0 + m0 + lane) * K + k0 + kc * 8,
              &As[kc * 1024 + m0 * 8]);
      async16(Bt + (size_t)(col0 + m0 + lane) * K + k0 + kc * 8,
              &Bs[kc * 1024 + m0 * 8]);
    }
    __syncthreads();

#pragma unroll
    for (int ks = 0; ks < 2; ++ks) {
      short8 af[4], bf[4];
      int plane = ks * 4 + quad;
#pragma unroll
      for (int im = 0; im < 4; ++im) {
        int m = wm * 64 + im * 16 + l15;
        af[im] = *(const short8*)&As[plane * 1024 + m * 8];
      }
#pragma unroll
      for (int in = 0; in < 4; ++in) {
        int n = wn * 64 + in * 16 + l15;
        bf[in] = *(const short8*)&Bs[plane * 1024 + n * 8];
      }
#pragma unroll
      for (int im = 0; im < 4; ++im)
#pragma unroll
        for (int in = 0; in < 4; ++in)
          acc[im][in] = __builtin_amdgcn_mfma_f32_16x16x32_bf16(
              af[im], bf[in], acc[im][in], 0, 0, 0);
    }
  }

  // epilogue: C/D layout col=lane&15, row=quad*4+reg
  if (MODE == 0) {
    const float QSCALE = 0.18033688f;  // 0.125 * log2(e)
#pragma unroll
    for (int im = 0; im < 4; ++im) {
      int mbase = row0 + wm * 64 + im * 16 + quad * 4;
      int bb = mbase >> 11, tb = mbase & 2047;  // constant across r (4-aligned)
#pragma unroll
      for (int in = 0; in < 4; ++in) {
        int n = col0 + wn * 64 + in * 16 + l15;
        float bv = bias[n];
        int which = n >> 10;  // uniform within frag
        int h = (n >> 6) & 15;
        int d = n & 63;
        size_t bhT = (size_t)(bb * 16 + h);
        if (which == 0) {
#pragma unroll
          for (int r = 0; r < 4; ++r)
            Qb[((bhT * 2048 + tb + r) << 6) + d] =
                f2bf((acc[im][in][r] + bv) * QSCALE);
        } else if (which == 1) {
#pragma unroll
          for (int r = 0; r < 4; ++r)
            Kb[((bhT * 2048 + tb + r) << 6) + d] = f2bf(acc[im][in][r] + bv);
        } else {
          short4v pk;
#pragma unroll
          for (int r = 0; r < 4; ++r)
            pk[r] = (short)f2bf(acc[im][in][r] + bv);
          *(short4v*)(Vt + ((bhT << 6) + d) * 2048 + tb) = pk;  // 8B packed
        }
      }
    }
  } else {
#pragma unroll
    for (int im = 0; im < 4; ++im) {
      int mbase = row0 + wm * 64 + im * 16 + quad * 4;
#pragma unroll
      for (int in = 0; in < 4; ++in) {
        int n = col0 + wn * 64 + in * 16 + l15;
        float bv = bias[n];
#pragma unroll
        for (int r = 0; r < 4; ++r)
          Cout[(size_t)(mbase + r) * N + n] = acc[im][in][r] + bv;
      }
    }
  }
}

// ---------------- MFMA flash attention ----------------
// 256 thr = 4 INDEPENDENT waves; wave w of block (bh, y) handles the
// 16-query strip s = (31-y)*4 + w (all 4 strips have equal ntiles).
// NO __syncthreads: P transpose uses a per-wave LDS buffer; LDS ops of a
// single wave complete in order, so write->read needs no barrier, and the
// prefetched K loads stay in flight across softmax+PV (no vmcnt(0) drain).
// Static-max exp2 softmax (Q prescaled by 0.125*log2e; logits bounded ~|10|),
// deferred l-reduction. Whole grid (1024 blocks) is co-resident.
__global__ __launch_bounds__(256) void attn_mfma(
    const unsigned short* __restrict__ Q, const unsigned short* __restrict__ K,
    const unsigned short* __restrict__ Vt, unsigned short* __restrict__ Y) {
  const int T = 2048, C = 1024;
  const int bh = blockIdx.x;
  const int wave = threadIdx.x >> 6;
  const int lane = threadIdx.x & 63;
  const int s = ((int)(gridDim.y - 1 - blockIdx.y)) * 4 + wave;  // 0..127
  const int quad = lane >> 4, l15 = lane & 15;

  __shared__ __align__(16) unsigned short Plds[4][16][72];
  unsigned short(*P)[72] = Plds[wave];

  const int t0 = s * 16;
  const unsigned short* Qb = Q + ((size_t)bh * T << 6);
  const unsigned short* Kb = K + ((size_t)bh * T << 6);
  const unsigned short* Vb = Vt + ((size_t)bh * T << 6);  // [64][2048]

  // Q A-frags: A[m=l15][k=quad*8+j], 2 k-chunks of 32
  short8 qf[2];
#pragma unroll
  for (int c = 0; c < 2; ++c)
    qf[c] = *(const short8*)(Qb + (((size_t)(t0 + l15)) << 6) + c * 32 + quad * 8);

  floatx4 o[4];
#pragma unroll
  for (int in = 0; in < 4; ++in) o[in] = (floatx4)0.0f;
  float l_acc[4] = {0.f, 0.f, 0.f, 0.f};

  const int ntiles = (s >> 2) + 1;

  short8 kf[4][2], vf[4][2];
  // preload K tile 0
#pragma unroll
  for (int in = 0; in < 4; ++in) {
    const unsigned short* kp = Kb + (((size_t)(in * 16 + l15)) << 6) + quad * 8;
    kf[in][0] = *(const short8*)(kp);
    kf[in][1] = *(const short8*)(kp + 32);
  }

  for (int jt = 0; jt < ntiles; ++jt) {
    const int kt0 = jt * 64;
    // V loads for this tile (consumed after softmax -> latency covered)
#pragma unroll
    for (int in = 0; in < 4; ++in) {
      const unsigned short* vp =
          Vb + (size_t)(in * 16 + l15) * 2048 + kt0 + quad * 8;
      vf[in][0] = *(const short8*)(vp);
      vf[in][1] = *(const short8*)(vp + 32);
    }

    // ---- S = Q K^T (C-layout: row=query=quad*4+r, col=key=in*16+l15) ----
    floatx4 sa[4];
#pragma unroll
    for (int in = 0; in < 4; ++in) {
      floatx4 z = (floatx4)0.0f;
      z = __builtin_amdgcn_mfma_f32_16x16x32_bf16(qf[0], kf[in][0], z, 0, 0, 0);
      sa[in] = __builtin_amdgcn_mfma_f32_16x16x32_bf16(qf[1], kf[in][1], z, 0, 0, 0);
    }

    // prefetch next K tile (stays in flight across softmax+transpose+PV —
    // nothing drains vmcnt before its use next iteration)
    if (jt + 1 < ntiles) {
      const int kt1 = kt0 + 64;
#pragma unroll
      for (int in = 0; in < 4; ++in) {
        const unsigned short* kp =
            Kb + (((size_t)(kt1 + in * 16 + l15)) << 6) + quad * 8;
        kf[in][0] = *(const short8*)(kp);
        kf[in][1] = *(const short8*)(kp + 32);
      }
    }

    // causal mask (last tile only)
    if (jt == ntiles - 1) {
#pragma unroll
      for (int in = 0; in < 4; ++in) {
        int key = kt0 + in * 16 + l15;
#pragma unroll
        for (int r = 0; r < 4; ++r)
          if (key > t0 + quad * 4 + r) sa[in][r] = -__builtin_inff();
      }
    }

    // ---- static-max softmax: p = 2^s, defer l reduction ----
#pragma unroll
    for (int in = 0; in < 4; ++in)
#pragma unroll
      for (int r = 0; r < 4; ++r) {
        float p = exp2f(sa[in][r]);
        sa[in][r] = p;
        l_acc[r] += p;
      }

    // ---- P -> per-wave LDS (bf16), C-layout -> A-layout transpose ----
#pragma unroll
    for (int in = 0; in < 4; ++in)
#pragma unroll
      for (int r = 0; r < 4; ++r)
        P[quad * 4 + r][in * 16 + l15] = f2bf(sa[in][r]);
    // in-order LDS per wave: reads below observe the writes above
    short8 pf0 = *(const short8*)&P[l15][quad * 8];
    short8 pf1 = *(const short8*)&P[l15][32 + quad * 8];

    // ---- O += P V ----
#pragma unroll
    for (int in = 0; in < 4; ++in) {
      o[in] = __builtin_amdgcn_mfma_f32_16x16x32_bf16(pf0, vf[in][0], o[in], 0, 0, 0);
      o[in] = __builtin_amdgcn_mfma_f32_16x16x32_bf16(pf1, vf[in][1], o[in], 0, 0, 0);
    }
  }

  // ---- one l reduction at the end (16-lane groups) ----
#pragma unroll
  for (int st = 1; st < 16; st <<= 1)
#pragma unroll
    for (int r = 0; r < 4; ++r) l_acc[r] += __shfl_xor(l_acc[r], st, 16);

  const int b_ = bh >> 4, h = bh & 15;
  float inv[4];
#pragma unroll
  for (int r = 0; r < 4; ++r) inv[r] = 1.f / l_acc[r];
#pragma unroll
  for (int in = 0; in < 4; ++in)
#pragma unroll
    for (int r = 0; r < 4; ++r)
      Y[(size_t)(b_ * T + t0 + quad * 4 + r) * C + h * 64 + in * 16 + l15] =
          f2bf(o[in][r] * inv[r]);
}

extern "C" void kernel_launch(void* const* d_in, const int* in_sizes, int n_in,
                              void* d_out, int out_size, void* d_ws,
                              size_t ws_size, hipStream_t stream) {
  const float* x = (const float*)d_in[0];      // [2,2048,1024]
  const float* Wqkv = (const float*)d_in[1];   // [1024,3072]
  const float* bqkv = (const float*)d_in[2];   // [3072]
  const float* Wproj = (const float*)d_in[3];  // [1024,1024]
  const float* bproj = (const float*)d_in[4];  // [1024]
  float* out = (float*)d_out;                  // [2,2048,1024]

  const int T = 2048, C = 1024;
  const int M = 4096;  // B*T

  // workspace layout (<=50 MiB):
  char* ws = (char*)d_ws;
  unsigned short* qbuf = (unsigned short*)ws;                  // 8 MiB bf16 [32][2048][64]
  unsigned short* kbuf = (unsigned short*)(ws + 8388608);      // 8 MiB
  unsigned short* vtbuf = (unsigned short*)(ws + 16777216);    // 8 MiB [32][64][2048]
  unsigned short* ybuf = (unsigned short*)(ws + 25165824);     // 8 MiB [4096][1024]
  unsigned short* xbf = (unsigned short*)(ws + 33554432);      // 8 MiB
  unsigned short* wqkvT = (unsigned short*)(ws + 41943040);    // 6 MiB [3072][1024]
  unsigned short* wprojT = (unsigned short*)(ws + 48234496);   // 2 MiB [1024][1024]

  dim3 blk(256);
  cvt_bf16<<<dim3(M * C / 4 / 256), blk, 0, stream>>>(x, xbf, M * C / 4);
  cvt_transpose<<<dim3(3 * C / 64, C / 64), blk, 0, stream>>>(Wqkv, wqkvT, C, 3 * C);
  cvt_transpose<<<dim3(C / 64, C / 64), blk, 0, stream>>>(Wproj, wprojT, C, C);
  // qkv GEMM -> bf16 Q (prescaled) / K / V^T
  gemm_bf16<0><<<dim3(3 * C / 128, M / 128), blk, 0, stream>>>(
      xbf, wqkvT, bqkv, nullptr, qbuf, kbuf, vtbuf, M, 3 * C, C);
  // MFMA flash attention -> y bf16 (4 indep waves per block, grid co-resident)
  attn_mfma<<<dim3(32, 32), blk, 0, stream>>>(qbuf, kbuf, vtbuf, ybuf);
  // proj GEMM -> out fp32
  gemm_bf16<1><<<dim3(C / 128, M / 128), blk, 0, stream>>>(
      ybuf, wprojT, bproj, out, nullptr, nullptr, nullptr, M, C, C);
}

// Round 7
// 218.183 us; speedup vs baseline: 1.4196x; 1.4196x over previous
//
#include <hip/hip_runtime.h>
#include <math.h>

// CausalSelfAttention: B=2, T=2048, C=1024, H=16, Dh=64. fp32 in/out.
//  1. cvt x -> bf16; cvt Wqkv/Wproj -> bf16 TRANSPOSED ([N][K])
//  2. bf16 MFMA GEMM qkv -> fragment-native tiled layouts (all attention
//     loads become lane*16B coalesced):
//       Q/K: [bh][t/16][d/8][t%16][8]   (Q prescaled by 0.125*log2e)
//       V:   [bh][d/16][t/8][d%16][8]
//  3. MFMA flash attention: S^T = K·Q^T (4-consecutive-key C-layout ->
//     b64 P writes), static-max exp2 softmax, scalar l, no barriers
//  4. bf16 MFMA GEMM out = y @ Wproj + bproj (fp32 out)

typedef __attribute__((ext_vector_type(8))) short short8;
typedef __attribute__((ext_vector_type(4))) short short4v;
typedef __attribute__((ext_vector_type(4))) float floatx4;

__device__ __forceinline__ unsigned short f2bf(float f) {
  unsigned u = __float_as_uint(f);
  return (unsigned short)((u + 0x7fff + ((u >> 16) & 1)) >> 16);
}

__device__ __forceinline__ void async16(const void* g, void* l) {
  __builtin_amdgcn_global_load_lds(
      (const __attribute__((address_space(1))) unsigned int*)g,
      (__attribute__((address_space(3))) unsigned int*)l, 16, 0, 0);
}

// ---------------- conversion kernels ----------------

__global__ __launch_bounds__(256) void cvt_bf16(const float* __restrict__ in,
                                                unsigned short* __restrict__ out,
                                                int n4) {
  int i = blockIdx.x * 256 + threadIdx.x;
  if (i < n4) {
    float4 v = ((const float4*)in)[i];
    uint2 p;
    p.x = (unsigned)f2bf(v.x) | ((unsigned)f2bf(v.y) << 16);
    p.y = (unsigned)f2bf(v.z) | ((unsigned)f2bf(v.w) << 16);
    ((uint2*)out)[i] = p;
  }
}

// in: [K][N] fp32 row-major; out: [N][K] bf16 row-major (transpose)
__global__ __launch_bounds__(256) void cvt_transpose(
    const float* __restrict__ in, unsigned short* __restrict__ out, int K, int N) {
  __shared__ __align__(16) unsigned short t[64][72];
  int k0 = blockIdx.y * 64, n0 = blockIdx.x * 64;
  int tid = threadIdx.x;
#pragma unroll
  for (int r = 0; r < 4; ++r) {
    int k = (tid >> 4) + r * 16;
    int n = (tid & 15) * 4;
    float4 v = *(const float4*)(in + (size_t)(k0 + k) * N + n0 + n);
    t[n + 0][k] = f2bf(v.x);
    t[n + 1][k] = f2bf(v.y);
    t[n + 2][k] = f2bf(v.z);
    t[n + 3][k] = f2bf(v.w);
  }
  __syncthreads();
#pragma unroll
  for (int r = 0; r < 2; ++r) {
    int n = (tid >> 3) + r * 32;
    int c = tid & 7;
    int4 v = *(const int4*)(&t[n][c * 8]);
    *(int4*)(out + (size_t)(n0 + n) * K + k0 + c * 8) = v;
  }
}

// ---------------- bf16 MFMA GEMM ----------------
// C[M,N] = A[M,K] @ B[K,N] + bias;  A: bf16 [M][K], Bt: bf16 [N][K] (B^T).
// 128x128 tile, BK=64, 4 waves (2x2 of 64x64), 16x16x32 bf16 MFMA.
// MODE 0: scatter to fragment-native Q/K/V layouts. MODE 1: fp32 row-major.
template <int MODE>
__global__ __launch_bounds__(256, 2) void gemm_bf16(
    const unsigned short* __restrict__ A, const unsigned short* __restrict__ Bt,
    const float* __restrict__ bias, float* __restrict__ Cout,
    unsigned short* __restrict__ Qb, unsigned short* __restrict__ Kb,
    unsigned short* __restrict__ Vt, int M, int N, int K) {
  __shared__ __align__(16) unsigned short As[8 * 1024];
  __shared__ __align__(16) unsigned short Bs[8 * 1024];

  const int tid = threadIdx.x;
  const int lane = tid & 63;
  const int wave = tid >> 6;
  const int wm = wave >> 1, wn = wave & 1;
  const int quad = lane >> 4;
  const int l15 = lane & 15;
  const int row0 = blockIdx.y * 128, col0 = blockIdx.x * 128;

  floatx4 acc[4][4];
#pragma unroll
  for (int i = 0; i < 4; ++i)
#pragma unroll
    for (int j = 0; j < 4; ++j) acc[i][j] = (floatx4)0.0f;

  for (int k0 = 0; k0 < K; k0 += 64) {
    __syncthreads();
#pragma unroll
    for (int ti = 0; ti < 4; ++ti) {
      int t = wave * 4 + ti;
      int kc = t >> 1;
      int m0 = (t & 1) << 6;
      async16(A + (size_t)(row0 + m0 + lane) * K + k0 + kc * 8,
              &As[kc * 1024 + m0 * 8]);
      async16(Bt + (size_t)(col0 + m0 + lane) * K + k0 + kc * 8,
              &Bs[kc * 1024 + m0 * 8]);
    }
    __syncthreads();

#pragma unroll
    for (int ks = 0; ks < 2; ++ks) {
      short8 af[4], bf[4];
      int plane = ks * 4 + quad;
#pragma unroll
      for (int im = 0; im < 4; ++im) {
        int m = wm * 64 + im * 16 + l15;
        af[im] = *(const short8*)&As[plane * 1024 + m * 8];
      }
#pragma unroll
      for (int in = 0; in < 4; ++in) {
        int n = wn * 64 + in * 16 + l15;
        bf[in] = *(const short8*)&Bs[plane * 1024 + n * 8];
      }
#pragma unroll
      for (int im = 0; im < 4; ++im)
#pragma unroll
        for (int in = 0; in < 4; ++in)
          acc[im][in] = __builtin_amdgcn_mfma_f32_16x16x32_bf16(
              af[im], bf[in], acc[im][in], 0, 0, 0);
    }
  }

  // epilogue: C/D layout col=lane&15, row=quad*4+reg
  if (MODE == 0) {
    const float QSCALE = 0.18033688f;  // 0.125 * log2(e)
#pragma unroll
    for (int im = 0; im < 4; ++im) {
      int mbase = row0 + wm * 64 + im * 16 + quad * 4;
      int bb = mbase >> 11, tb = mbase & 2047;  // tb&15 == quad*4
#pragma unroll
      for (int in = 0; in < 4; ++in) {
        int n = col0 + wn * 64 + in * 16 + l15;
        float bv = bias[n];
        int which = n >> 10;  // uniform within frag
        int h = (n >> 6) & 15;
        int d = n & 63;
        size_t bh_ = (size_t)(bb * 16 + h);
        if (which == 2) {
          // V: [bh][d/16][t/8][d%16][8], r = consecutive t -> 8B packed
          size_t base = bh_ * 131072 + (size_t)(d >> 4) * 32768 +
                        (size_t)(tb >> 3) * 128 + (d & 15) * 8 + (tb & 7);
          short4v pk;
#pragma unroll
          for (int r = 0; r < 4; ++r) pk[r] = (short)f2bf(acc[im][in][r] + bv);
          *(short4v*)(Vt + base) = pk;
        } else {
          // Q/K: [bh][t/16][d/8][t%16][8], r -> +8 shorts
          size_t base = bh_ * 131072 + (size_t)(tb >> 4) * 1024 +
                        (d >> 3) * 128 + (tb & 15) * 8 + (d & 7);
          if (which == 0) {
#pragma unroll
            for (int r = 0; r < 4; ++r)
              Qb[base + r * 8] = f2bf((acc[im][in][r] + bv) * QSCALE);
          } else {
#pragma unroll
            for (int r = 0; r < 4; ++r)
              Kb[base + r * 8] = f2bf(acc[im][in][r] + bv);
          }
        }
      }
    }
  } else {
#pragma unroll
    for (int im = 0; im < 4; ++im) {
      int mbase = row0 + wm * 64 + im * 16 + quad * 4;
#pragma unroll
      for (int in = 0; in < 4; ++in) {
        int n = col0 + wn * 64 + in * 16 + l15;
        float bv = bias[n];
#pragma unroll
        for (int r = 0; r < 4; ++r)
          Cout[(size_t)(mbase + r) * N + n] = acc[im][in][r] + bv;
      }
    }
  }
}

// ---------------- MFMA flash attention ----------------
// 256 thr = 4 INDEPENDENT waves; wave w of block (bh, y) handles the
// 16-query strip s = (31-y)*4 + w (equal ntiles within a block, LPT across).
// All Q/K/V fragment loads are contiguous-1KB-per-instruction (fragment-
// native layouts written by the qkv GEMM). S^T = K·Q^T so the C-layout holds
// 4 consecutive keys -> P transpose = 4x b64 LDS writes (per-wave buffer,
// in-order LDS, no barriers). Static-max exp2 softmax, scalar deferred l.
__global__ __launch_bounds__(256) void attn_mfma(
    const unsigned short* __restrict__ Q, const unsigned short* __restrict__ K,
    const unsigned short* __restrict__ Vt, unsigned short* __restrict__ Y) {
  const int T = 2048, C = 1024;
  const int bh = blockIdx.x;
  const int wave = threadIdx.x >> 6;
  const int lane = threadIdx.x & 63;
  const int s = ((int)(gridDim.y - 1 - blockIdx.y)) * 4 + wave;  // 0..127
  const int quad = lane >> 4, l15 = lane & 15;

  __shared__ __align__(16) unsigned short Plds[4][16][72];
  unsigned short(*P)[72] = Plds[wave];

  const int t0 = s * 16;
  const unsigned short* Qb = Q + (size_t)bh * 131072;
  const unsigned short* Kb = K + (size_t)bh * 131072;
  const unsigned short* Vb = Vt + (size_t)bh * 131072;
  const int lofs = quad * 128 + l15 * 8;  // == lane*8 shorts (16B/lane)

  // Q frags: A/B[m or n = l15][k = c*32+quad*8+j]
  short8 qf[2];
#pragma unroll
  for (int c = 0; c < 2; ++c)
    qf[c] = *(const short8*)(Qb + (size_t)s * 1024 + c * 512 + lofs);

  floatx4 o[4];
#pragma unroll
  for (int in = 0; in < 4; ++in) o[in] = (floatx4)0.0f;
  float l_acc = 0.f;

  const int ntiles = (s >> 2) + 1;

  short8 kf[4][2], vf[4][2];
  // preload K tile 0
#pragma unroll
  for (int in = 0; in < 4; ++in) {
    const unsigned short* kp = Kb + (size_t)in * 1024 + lofs;
    kf[in][0] = *(const short8*)(kp);
    kf[in][1] = *(const short8*)(kp + 512);
  }

  for (int jt = 0; jt < ntiles; ++jt) {
    const int kt0 = jt * 64;
    // V loads for this tile (consumed after softmax -> latency covered)
#pragma unroll
    for (int in = 0; in < 4; ++in) {
      const unsigned short* vp =
          Vb + (size_t)in * 32768 + (size_t)jt * 1024 + lofs;
      vf[in][0] = *(const short8*)(vp);
      vf[in][1] = *(const short8*)(vp + 512);
    }

    // ---- S^T = K Q^T (C-layout: row=key=quad*4+r (+16in), col=query=l15)
    floatx4 sa[4];
#pragma unroll
    for (int in = 0; in < 4; ++in) {
      floatx4 z = (floatx4)0.0f;
      z = __builtin_amdgcn_mfma_f32_16x16x32_bf16(kf[in][0], qf[0], z, 0, 0, 0);
      sa[in] = __builtin_amdgcn_mfma_f32_16x16x32_bf16(kf[in][1], qf[1], z, 0, 0, 0);
    }

    // prefetch next K tile (stays in flight across softmax+PV)
    if (jt + 1 < ntiles) {
#pragma unroll
      for (int in = 0; in < 4; ++in) {
        const unsigned short* kp =
            Kb + (size_t)(jt * 4 + 4 + in) * 1024 + lofs;
        kf[in][0] = *(const short8*)(kp);
        kf[in][1] = *(const short8*)(kp + 512);
      }
    }

    // causal mask (last tile only): key > query -> -inf
    if (jt == ntiles - 1) {
#pragma unroll
      for (int in = 0; in < 4; ++in) {
        int keyb = kt0 + in * 16 + quad * 4;
#pragma unroll
        for (int r = 0; r < 4; ++r)
          if (keyb + r > t0 + l15) sa[in][r] = -__builtin_inff();
      }
    }

    // ---- static-max softmax: p = 2^s; all 16 regs share query l15 ----
#pragma unroll
    for (int in = 0; in < 4; ++in)
#pragma unroll
      for (int r = 0; r < 4; ++r) {
        float p = exp2f(sa[in][r]);
        sa[in][r] = p;
        l_acc += p;
      }

    // ---- P[query=l15][key] bf16 (truncated), one b64 write per in ----
#pragma unroll
    for (int in = 0; in < 4; ++in) {
      uint2 pk;
      pk.x = (__float_as_uint(sa[in][0]) >> 16) |
             (__float_as_uint(sa[in][1]) & 0xFFFF0000u);
      pk.y = (__float_as_uint(sa[in][2]) >> 16) |
             (__float_as_uint(sa[in][3]) & 0xFFFF0000u);
      *(uint2*)&P[l15][in * 16 + quad * 4] = pk;
    }
    // in-order per-wave LDS: reads below observe the writes above
    short8 pf0 = *(const short8*)&P[l15][quad * 8];
    short8 pf1 = *(const short8*)&P[l15][32 + quad * 8];

    // ---- O += P V ----
#pragma unroll
    for (int in = 0; in < 4; ++in) {
      o[in] = __builtin_amdgcn_mfma_f32_16x16x32_bf16(pf0, vf[in][0], o[in], 0, 0, 0);
      o[in] = __builtin_amdgcn_mfma_f32_16x16x32_bf16(pf1, vf[in][1], o[in], 0, 0, 0);
    }
  }

  // ---- l: reduce over quad lanes; every lane ends with L[l15] ----
  l_acc += __shfl_xor(l_acc, 16);
  l_acc += __shfl_xor(l_acc, 32);

  const int b_ = bh >> 4, h = bh & 15;
  float inv[4];
#pragma unroll
  for (int r = 0; r < 4; ++r)
    inv[r] = 1.f / __shfl(l_acc, (lane & 48) | (quad * 4 + r));
#pragma unroll
  for (int in = 0; in < 4; ++in)
#pragma unroll
    for (int r = 0; r < 4; ++r)
      Y[(size_t)(b_ * T + t0 + quad * 4 + r) * C + h * 64 + in * 16 + l15] =
          f2bf(o[in][r] * inv[r]);
}

extern "C" void kernel_launch(void* const* d_in, const int* in_sizes, int n_in,
                              void* d_out, int out_size, void* d_ws,
                              size_t ws_size, hipStream_t stream) {
  const float* x = (const float*)d_in[0];      // [2,2048,1024]
  const float* Wqkv = (const float*)d_in[1];   // [1024,3072]
  const float* bqkv = (const float*)d_in[2];   // [3072]
  const float* Wproj = (const float*)d_in[3];  // [1024,1024]
  const float* bproj = (const float*)d_in[4];  // [1024]
  float* out = (float*)d_out;                  // [2,2048,1024]

  const int C = 1024;
  const int M = 4096;  // B*T

  // workspace layout (<=50 MiB):
  char* ws = (char*)d_ws;
  unsigned short* qbuf = (unsigned short*)ws;                  // 8 MiB
  unsigned short* kbuf = (unsigned short*)(ws + 8388608);      // 8 MiB
  unsigned short* vtbuf = (unsigned short*)(ws + 16777216);    // 8 MiB
  unsigned short* ybuf = (unsigned short*)(ws + 25165824);     // 8 MiB [4096][1024]
  unsigned short* xbf = (unsigned short*)(ws + 33554432);      // 8 MiB
  unsigned short* wqkvT = (unsigned short*)(ws + 41943040);    // 6 MiB [3072][1024]
  unsigned short* wprojT = (unsigned short*)(ws + 48234496);   // 2 MiB [1024][1024]

  dim3 blk(256);
  cvt_bf16<<<dim3(M * C / 4 / 256), blk, 0, stream>>>(x, xbf, M * C / 4);
  cvt_transpose<<<dim3(3 * C / 64, C / 64), blk, 0, stream>>>(Wqkv, wqkvT, C, 3 * C);
  cvt_transpose<<<dim3(C / 64, C / 64), blk, 0, stream>>>(Wproj, wprojT, C, C);
  // qkv GEMM -> fragment-native Q (prescaled) / K / V layouts
  gemm_bf16<0><<<dim3(3 * C / 128, M / 128), blk, 0, stream>>>(
      xbf, wqkvT, bqkv, nullptr, qbuf, kbuf, vtbuf, M, 3 * C, C);
  // MFMA flash attention -> y bf16
  attn_mfma<<<dim3(32, 32), blk, 0, stream>>>(qbuf, kbuf, vtbuf, ybuf);
  // proj GEMM -> out fp32
  gemm_bf16<1><<<dim3(C / 128, M / 128), blk, 0, stream>>>(
      ybuf, wprojT, bproj, out, nullptr, nullptr, nullptr, M, C, C);
}